// Round 14
// baseline (1221.137 us; speedup 1.0000x reference)
//
#include <hip/hip_runtime.h>
#include <hip/hip_bf16.h>
#include <stdint.h>

// SymmetricHyperRBM on MI355X. K=10 Gibbs chain + free-energy gap.
// R27: chain K-loop stages A ONLY; B fragments read DIRECT FROM GLOBAL
// (L1-shared). Diagnosis after 4 structural nulls (R18/R22/R24/R26): the
// chain loop is bound by combined LDS-pipe traffic (stage-write + A-frag +
// B-frag ~192 KB/CU/iter ~1500cy vs 600cy compute), not by the barrier.
// B (Wt/Wb) is the shared, L1/L2-hot panel; direct dwordx4 at
// row*LDA + it*64 + quad*16 IS the canonical i8 K=64 B-fragment (lane holds
// k=quad*16..+15) — bit-identical to the swizzled-LDS path. LDS/CU/iter
// halves to ~96 KB; B latency TLP-hidden (occupancy unchanged: 32 KB LDS,
// 4 blk/CU grid-limited). Chain keeps 2-buffer + ONE __syncthreads/iter.
// EPI2 unchanged (single 12KB buffer, A+B staged). R25 carried: k_prepw.
// R23: vectorized k_sinit, parallel k_wcs. R21: i8 mfma 16x16x64, states
// {0,7}, p=2^-13, exact i32 (absmax 0.0). R20: NT=17 unroll. R19: KD=1088.

#define NB 16384
#define KSTEPS 10
#define LDA 1152           // bytes/row: 1024 state + 64 X + 1 const + 63 pad
#define KD 1088            // GEMM K-dim: 1024 state + 64 X (cst in epilogue)
#define NT 17              // KD/64 K-iterations (compile-time, fully unrolled)
#define SLS 136            // epilogue slab row stride in bytes (128 + 8 pad)
#define USALT 4000u
#define BONE ((unsigned char)7)     // binary-one storage value (i8)
#define PSC 0x1.0p-13f              // common int->value scale p
#define RWQ 1170.2857142857f        // 8192/7: W & cst quantizer
#define SGQ 64.0f                   // G quantizer
#define SXQ 128.0f                  // X quantizer

typedef __attribute__((ext_vector_type(4))) float f32x4;
typedef __attribute__((ext_vector_type(4))) int i32x4;
typedef __attribute__((ext_vector_type(4))) unsigned int u32x4;

__device__ __forceinline__ unsigned hash32(unsigned idx, unsigned salt) {
  unsigned x = idx + salt * 0x9E3779B9u;
  x = (x ^ (x >> 16)) * 0x7feb352du;
  x = (x ^ (x >> 15)) * 0x846ca68bu;
  return x ^ (x >> 16);
}
__device__ __forceinline__ float rng_u01(unsigned salt, unsigned idx) {
  return (float)(hash32(idx, salt) >> 8) * (1.0f / 16777216.0f);
}
__device__ __forceinline__ float sigm(float z) { return 1.0f / (1.0f + __expf(-z)); }
// fast softplus: max(z,0) + log(1+exp(-|z|)); v_exp/v_log based.
__device__ __forceinline__ float softplus_(float z) {
  return fmaxf(z, 0.f) + __logf(1.f + __expf(-fabsf(z)));
}
__device__ __forceinline__ float lse2(float a, float b) {
  float m = fmaxf(a, b);
  return m + log1pf(__expf(fminf(a, b) - m));
}
// saturating i8 quantizer (returns bit pattern)
__device__ __forceinline__ unsigned char qi8(float v, float s) {
  float x = rintf(v * s);
  x = fminf(fmaxf(x, -127.f), 127.f);
  return (unsigned char)(signed char)(int)x;
}
__device__ __forceinline__ void gl2lds16(const void* g, void* l) {
  __builtin_amdgcn_global_load_lds(
      (const __attribute__((address_space(1))) unsigned int*)g,
      (__attribute__((address_space(3))) unsigned int*)l, 16, 0, 0);
}

// ---------------------------------------------------------------------------
// C = A[16384 x KD] *i8* Bt[. x KD]^T (epilogue: z = acc*PSC + cst),
// mfma_i32_16x16x64_i8, BK=64, NT=17 fully unrolled.
// Chain (EPI0/1): BM=128, 4 waves x 64x64, grid 1024; A-only 2x8KB LDS
//   dbuf + B-frags direct from global (R27); ONE __syncthreads/iter.
//   LDS map: [Abuf0 8K][Abuf1 8K][old-S 16K]; slab 0..17408 post-loop.
//   xcd=L&7, li=L>>3; m0=xcd*2048+(li&15)*128; n-tile=li>>4.
// EPI2: BM=64, 4 waves x 32x64, grid 2304 (incl. bias n-tile 8), single
//   12KB buffer (A+B staged: stage->sync->compute->sync).
// EPI 0: h = bern(sigm(z1)) -> sh. EPI 1: u_t inline; p0+=sum z, p1+=sum v*z
// (v via LDS-staged old-S tile); s_new -> sh. EPI 2: split-acc (acc it<16 =
// vW; accf it==16 = X.Gc); n<8 softplus rows; n==8 bias-dots.
// ---------------------------------------------------------------------------
template <int EPI>
__global__ __launch_bounds__(256, 4) void gemm_bt(
    const unsigned char* __restrict__ A, const unsigned char* __restrict__ Bt,
    unsigned char* sh, const float* __restrict__ cst,
    const float* __restrict__ wcs, const float* __restrict__ Xf,
    const float* __restrict__ pv0, const float* __restrict__ pv1, unsigned usalt,
    float* __restrict__ p0, float* __restrict__ p1, float* __restrict__ p2,
    unsigned salt) {
  constexpr int MI = (EPI == 2 ? 2 : 4);   // 16-row tiles per wave (M dir)
  constexpr int BM = MI * 32;              // block rows: 64 (EPI2) / 128
  constexpr int ABYT = BM * 64;            // A-panel bytes/buffer: 4K / 8K
  constexpr int NLDS = (EPI == 2 ? ABYT + 8192 : 32768);
  __shared__ __align__(16) char smem[NLDS];
  unsigned char* newsl = (unsigned char*)smem;

  const int t = threadIdx.x;
  const int L = blockIdx.x;
  const int xcd = L & 7, li = L >> 3;
  constexpr int MMSK = (EPI == 2 ? 31 : 15);
  constexpr int NSH = (EPI == 2 ? 5 : 4);
  const int m0 = xcd * 2048 + (li & MMSK) * BM;
  const int n0 = (li >> NSH) * 128;
  const int lane = t & 63, wave = t >> 6;
  const int wm = (wave >> 1) * (MI * 16), wn = (wave & 1) * 64;
  const int lr = lane & 15, quad = lane >> 4;
  // staging: lane -> row = lane>>2, phys chunk lane&3; gathers LOGICAL chunk
  // q = (lane&3) ^ (row&3) ^ ((lane>>4)&3)   [double-XOR swizzle]
  const int row8 = lane >> 2;
  const int qch = (((lane & 3) ^ (row8 & 3) ^ ((lane >> 4) & 3)) << 4);
  // i8 K=64 fragment from LDS: logical chunk = quad; phys = quad ^ rx(row).
  const int rx = (lr & 3) ^ ((lr >> 2) & 3);
  const int kph = ((quad ^ rx) << 4);

  // staging base pointers
  const unsigned char* gA0 = A + (size_t)(m0 + wave * (MI * 8) + row8) * LDA + qch;
  const unsigned char* gA1 = gA0 + (size_t)16 * LDA;  // chain only
  const unsigned char* gB0 = Bt + (size_t)(n0 + wave * 32 + row8) * LDA + qch;
  const unsigned char* gB1 = gB0 + (size_t)16 * LDA;  // EPI2 staging only
  // chain: direct B-fragment base (canonical layout, no swizzle needed)
  const unsigned char* gBf = Bt + (size_t)(n0 + wn + lr) * LDA + quad * 16;

  i32x4 acc[MI][4] = {};
  i32x4 accf[EPI == 2 ? MI : 1][4] = {};  // EPI2 only: FiLM iter = X.Gc

  if constexpr (EPI == 2) {
    // single-buffer loop: 12KB LDS, stage(A+B)->sync->compute->sync.
#pragma unroll
    for (int it = 0; it < NT; ++it) {
      const int ko = it * 64;
      gl2lds16(gA0 + ko, smem + wave * 1024);
      gl2lds16(gB0 + ko, smem + ABYT + wave * 2048);
      gl2lds16(gB1 + ko, smem + ABYT + wave * 2048 + 1024);
      __syncthreads();  // drains vmcnt -> staged tile published
      const char* sA = (const char*)smem;
      const char* sB = sA + ABYT;
      i32x4 af[MI], bfr[4];
#pragma unroll
      for (int i = 0; i < MI; i++)
        af[i] = *(const i32x4*)(sA + (wm + i * 16 + lr) * 64 + kph);
#pragma unroll
      for (int j = 0; j < 4; j++)
        bfr[j] = *(const i32x4*)(sB + (wn + j * 16 + lr) * 64 + kph);
      if (it >= 16) {  // FiLM iter (k 1024..1087) -> accf
#pragma unroll
        for (int i = 0; i < MI; i++)
#pragma unroll
          for (int j = 0; j < 4; j++)
            accf[i][j] = __builtin_amdgcn_mfma_i32_16x16x64_i8(af[i], bfr[j], accf[i][j], 0, 0, 0);
      } else {
#pragma unroll
        for (int i = 0; i < MI; i++)
#pragma unroll
          for (int j = 0; j < 4; j++)
            acc[i][j] = __builtin_amdgcn_mfma_i32_16x16x64_i8(af[i], bfr[j], acc[i][j], 0, 0, 0);
      }
      __syncthreads();  // all reads done before next stage overwrites
    }
  } else {
    // chain: A-only double-buffer + global-B fragments (R27).
    gl2lds16(gA0, smem + wave * 2048);
    gl2lds16(gA1, smem + wave * 2048 + 1024);
    __syncthreads();
#pragma unroll
    for (int it = 0; it < NT; ++it) {
      const int base = (it & 1) * 8192;       // compile-time per body
      const int ko = (it + 1) * 64;
      if (it + 1 < NT) {
        gl2lds16(gA0 + ko, smem + (base ^ 8192) + wave * 2048);
        gl2lds16(gA1 + ko, smem + (base ^ 8192) + wave * 2048 + 1024);
      }
      // B fragments direct from global: row n0+wn+j*16+lr, k it*64+quad*16.
      // Panel is L1-resident (8 KB/iter, shared by 2 waves; Wt/Wb L2-hot
      // chip-wide). Issued first so latency hides under A reads + MFMAs.
      i32x4 bfr[4];
#pragma unroll
      for (int j = 0; j < 4; j++)
        bfr[j] = *(const i32x4*)(gBf + (size_t)j * 16 * LDA + it * 64);
      const char* sA = (const char*)smem + base;
      i32x4 af[MI];
#pragma unroll
      for (int i = 0; i < MI; i++)
        af[i] = *(const i32x4*)(sA + (wm + i * 16 + lr) * 64 + kph);
#pragma unroll
      for (int i = 0; i < MI; i++)
#pragma unroll
        for (int j = 0; j < 4; j++)
          acc[i][j] = __builtin_amdgcn_mfma_i32_16x16x64_i8(af[i], bfr[j], acc[i][j], 0, 0, 0);
      // ONE barrier per iter: its vmcnt(0) drain covers the A prefetch (in
      // flight across the whole compute phase; B arrivals were already
      // forced by their MFMAs) and orders reads-of-base before overwrite.
      __syncthreads();
    }
  }

  // per-thread cst values for this thread's 4 column slots (L1-resident)
  float cst_j[4];
  if constexpr (EPI != 2) {
#pragma unroll
    for (int j = 0; j < 4; j++) cst_j[j] = cst[n0 + wn + j * 16 + lr];
  }

  // C/D layout (m89, dtype-independent): col = lane&15, row = quad*4 + reg
  if constexpr (EPI == 2) {
    if (n0 >= 1024) {  // bias-dot tile: cols 1024..1088 = [Gb-dots | cstb]
#pragma unroll
      for (int i = 0; i < MI; i++)
#pragma unroll
        for (int rg = 0; rg < 4; rg++) {
          const int r = m0 + wm + i * 16 + quad * 4 + rg;
          float pb = 0.f;
          if (wn == 0) {  // cg = j*16+lr in 0..63: G-dots with X[r]
#pragma unroll
            for (int j = 0; j < 4; j++)
              pb += (float)acc[i][j][rg] * Xf[(size_t)r * 64 + j * 16 + lr];
            pb *= (1.f / 448.f);            // /(7 * SGQ)
          } else {        // col 1088 (j==0,lr==0): cst-dot
            if (lr == 0) pb = (float)acc[i][0][rg] * PSC;
          }
#pragma unroll
          for (int msk = 1; msk < 16; msk <<= 1) pb += __shfl_xor(pb, msk, 64);
          if (lr == 0) atomicAdd(&p2[r], pb);
        }
      return;
    }
    float cstc_j[4];
#pragma unroll
    for (int j = 0; j < 4; j++) cstc_j[j] = cst[n0 + wn + j * 16 + lr];
#pragma unroll
    for (int i = 0; i < MI; i++)
#pragma unroll
      for (int rg = 0; rg < 4; rg++) {
        const int r = m0 + wm + i * 16 + quad * 4 + rg;
        bool uu = true;
        if (pv0 != nullptr) {
          const float dE = -pv0[r] + 2.f * pv1[r];
          uu = rng_u01(usalt, (unsigned)r) < sigm(dE);
        }
        float sn = 0.f, sf = 0.f;
#pragma unroll
        for (int j = 0; j < 4; j++) {
          const int n = n0 + wn + j * 16 + lr;
          const float vw = (float)acc[i][j][rg] * PSC;
          const float cm = (float)accf[i][j][rg] * PSC + cstc_j[j];
          const float s1 = softplus_(vw + cm);
          const float s2 = softplus_(wcs[n] - vw + cm);
          sn += uu ? s1 : s2;
          sf += uu ? s2 : s1;
        }
#pragma unroll
        for (int msk = 1; msk < 16; msk <<= 1) {
          sn += __shfl_xor(sn, msk, 64);
          sf += __shfl_xor(sf, msk, 64);
        }
        if (lr == 0) { atomicAdd(&p0[r], sn); atomicAdd(&p1[r], sf); }
      }
    return;
  }

  if constexpr (EPI == 1) {  // z-sums with v from OLD s; u_t inline
    // Stage this block's OLD-S tile (128 x 128 B) into [16K, 32K).
    // m173: linear LDS dest + PRE-SWIZZLED global source, so lds chunk c of
    // row r holds global chunk c ^ ((r>>2)&3).
    {
      const int rb = wave * 32;                 // 32 rows per wave
#pragma unroll
      for (int q = 0; q < 4; ++q) {
        const int row = rb + q * 8 + (lane >> 3);
        const int sc = (lane & 7) ^ ((row >> 2) & 3);
        gl2lds16(sh + (size_t)(m0 + row) * LDA + n0 + sc * 16,
                 (unsigned char*)smem + 16384 + (rb + q * 8) * 128);
      }
    }
    __syncthreads();  // drains vmcnt -> old-S tile published in LDS
    const unsigned char* osl = (const unsigned char*)smem + 16384;
#pragma unroll
    for (int i = 0; i < MI; i++)
#pragma unroll
      for (int rg = 0; rg < 4; rg++) {
        const int r = m0 + wm + i * 16 + quad * 4 + rg;
        const int rowl = wm + i * 16 + quad * 4 + rg;
        const float dE = -pv0[r] + 2.f * pv1[r];
        const bool uu = rng_u01(usalt, (unsigned)r) < sigm(dE);
        float q0 = 0.f, q1 = 0.f;
#pragma unroll
        for (int j = 0; j < 4; ++j) {
          const float z = (float)acc[i][j][rg] * PSC + cst_j[j];
          // read-side swizzle: (rowl>>2)&3 == quad for our row decomposition
          const int pc = ((wn >> 4) + j) ^ quad;
          const float so = (osl[rowl * 128 + pc * 16 + lr] != 0) ? 1.f : 0.f;
          const float v = uu ? so : 1.f - so;
          q0 += z; q1 += v * z;
        }
#pragma unroll
        for (int msk = 1; msk < 16; msk <<= 1) {
          q0 += __shfl_xor(q0, msk, 64);
          q1 += __shfl_xor(q1, msk, 64);
        }
        if (lr == 0) { atomicAdd(&p0[r], q0); atomicAdd(&p1[r], q1); }
      }
    __syncthreads();  // old-S reads done before slab overwrites [16K,17408)
  }

  // EPI 0/1: sample into BM-row slab, 1 barrier, coalesced store
#pragma unroll
  for (int i = 0; i < MI; ++i)
#pragma unroll
    for (int rg = 0; rg < 4; ++rg) {
      const int rowl = wm + i * 16 + quad * 4 + rg;  // 0..BM-1 in tile
      const int r = m0 + rowl;
#pragma unroll
      for (int jp = 0; jp < 2; ++jp) {
        const unsigned x = hash32((unsigned)(r << 10) + (unsigned)(n0 + wn + jp * 16 + lr), salt);
        const float f0 = (float)(x & 0xFFFFu), f1 = (float)(x >> 16);
        const float z0 = (float)acc[i][jp][rg] * PSC + cst_j[jp];
        const float z1v = (float)acc[i][jp + 2][rg] * PSC + cst_j[jp + 2];
        newsl[rowl * SLS + wn + jp * 16 + lr] =
            (f0 * __expf(-z0) < 65536.f - f0) ? BONE : (unsigned char)0;
        newsl[rowl * SLS + wn + (jp + 2) * 16 + lr] =
            (f1 * __expf(-z1v) < 65536.f - f1) ? BONE : (unsigned char)0;
      }
    }
  __syncthreads();
#pragma unroll
  for (int p = 0; p < BM / 32; ++p) {  // BM rows x 128 B, fully coalesced
    const int c = p * 256 + t, rowl = c >> 3, chk = c & 7;
    const u32x4 vv = *(const u32x4*)(newsl + rowl * SLS + chk * 16);
    *(u32x4*)(sh + (size_t)(m0 + rowl) * LDA + n0 + chk * 16) = vv;
  }
}

// ------------------------- setup / small kernels ---------------------------
__global__ __launch_bounds__(256) void k_x(const float* __restrict__ cond,
                                           const float* __restrict__ fc1w,
                                           const float* __restrict__ fc1b, float* __restrict__ X) {
  int idx = blockIdx.x * 256 + threadIdx.x;
  int r = idx >> 6, k = idx & 63;
  X[idx] = tanhf(cond[r] * fc1w[k] + fc1b[k]);
}

__global__ __launch_bounds__(256) void k_g(const float* __restrict__ fc2w,
                                           const float* __restrict__ fc2b,
                                           const float* __restrict__ b, const float* __restrict__ c,
                                           float* __restrict__ Gb, float* __restrict__ Gc,
                                           float* __restrict__ cstb, float* __restrict__ cstc) {
  int idx = blockIdx.x * 256 + threadIdx.x;
  int j = idx >> 6, k = idx & 63;
  Gb[idx] = fc2w[(size_t)j * 64 + k] * b[j] + fc2w[(size_t)(1024 + j) * 64 + k];
  Gc[idx] = fc2w[(size_t)(2048 + j) * 64 + k] * c[j] + fc2w[(size_t)(3072 + j) * 64 + k];
  if (k == 0) {
    cstb[j] = b[j] + fc2b[j] * b[j] + fc2b[1024 + j];
    cstc[j] = c[j] + fc2b[2048 + j] * c[j] + fc2b[3072 + j];
  }
}

// LDS-transpose pack of the 1024^2 W block: coalesced read of a 64x64 tile,
// Wb (direct) and Wt (transposed) written 16B/thread. Same qi8 -> outputs
// bitwise-identical to the old per-element path.
__global__ __launch_bounds__(256) void k_prepw(const float* __restrict__ W,
                                               unsigned char* __restrict__ Wt,
                                               unsigned char* __restrict__ Wb) {
  __shared__ float tile[64][65];
  const int t = threadIdx.x;
  const int a0 = blockIdx.x * 64, b0 = blockIdx.y * 64;
#pragma unroll
  for (int e = 0; e < 16; ++e) {
    const int idx = e * 256 + t;
    tile[idx >> 6][idx & 63] = W[(size_t)(a0 + (idx >> 6)) * 1024 + b0 + (idx & 63)];
  }
  __syncthreads();
  const int r = t >> 2, c = (t & 3) * 16;
  union { u32x4 v4; unsigned char b[16]; } pb, pt;
#pragma unroll
  for (int e = 0; e < 16; ++e) {
    pb.b[e] = qi8(tile[r][c + e], RWQ);   // Wb[a0+r][b0+c+e] = W[n][k]
    pt.b[e] = qi8(tile[c + e][r], RWQ);   // Wt[b0+r][a0+c+e] = W[k][n]
  }
  *(u32x4*)(Wb + (size_t)(a0 + r) * LDA + b0 + c) = pb.v4;
  *(u32x4*)(Wt + (size_t)(b0 + r) * LDA + a0 + c) = pt.v4;
}

// i8 pack of the non-W regions (W 1024^2 handled by k_prepw).
// Wt rows n<1024: [..|Gc(SGQ)|cst|pad]; rows 1024..1087: Gb-col profiles
// (SGQ); row 1088: cstb (RWQ). Wb mirror. Rows >=1024 zero at k>=1024.
__global__ __launch_bounds__(256) void k_prep(const float* __restrict__ W,
                                              const float* __restrict__ Gb,
                                              const float* __restrict__ Gc,
                                              const float* __restrict__ cstb,
                                              const float* __restrict__ cstc,
                                              unsigned char* __restrict__ Wt,
                                              unsigned char* __restrict__ Wb) {
  int k = blockIdx.x * 256 + threadIdx.x;
  int n = blockIdx.y;
  if (k >= LDA) return;
  if (n < 1024 && k < 1024) return;  // W block done by k_prepw
  unsigned char wt = 0, wb = 0;
  if (n < 1024) {
    if (k < 1088) {
      int j = k - 1024;
      wt = qi8(Gc[(size_t)n * 64 + j], SGQ);
      wb = qi8(Gb[(size_t)n * 64 + j], SGQ);
    } else if (k == 1088) {  // unused at KD=1088
      wt = qi8(cstc[n], RWQ);
      wb = qi8(cstb[n], RWQ);
    }
  } else if (k < 1024) {
    if (n < 1088) wt = qi8(Gb[(size_t)k * 64 + (n - 1024)], SGQ);
    else if (n == 1088) wt = qi8(cstb[k], RWQ);
  }
  Wt[(size_t)n * LDA + k] = wt;
  Wb[(size_t)n * LDA + k] = wb;
}

// 64 blocks x (256 n, 64 i) partials + atomicAdd (wcs pre-zeroed)
__global__ __launch_bounds__(256) void k_wcs(const float* __restrict__ W, float* __restrict__ wcs) {
  int n = blockIdx.x * 256 + threadIdx.x;
  int i0 = blockIdx.y * 64;
  float s = 0.f;
  for (int i = i0; i < i0 + 64; i++) s += W[(size_t)i * 1024 + n];
  atomicAdd(&wcs[n], s);
}

// aux[k<64] = sum_j Gb[j][k]; aux[64] = sum_j cstb[j]
__global__ __launch_bounds__(128) void k_aux(const float* __restrict__ Gb,
                                             const float* __restrict__ cstb,
                                             float* __restrict__ aux) {
  int t = threadIdx.x;
  if (t < 64) {
    float s = 0.f;
    for (int j = 0; j < 1024; j++) s += Gb[(size_t)j * 64 + t];
    aux[t] = s;
  } else if (t == 64) {
    float s = 0.f;
    for (int j = 0; j < 1024; j++) s += cstb[j];
    aux[64] = s;
  }
}

// vectorized init: one 16-B chunk per thread.
__global__ __launch_bounds__(256) void k_sinit(const float* __restrict__ vdata,
                                               const float* __restrict__ X,
                                               unsigned char* __restrict__ S,
                                               unsigned char* __restrict__ H,
                                               unsigned char* __restrict__ V) {
  const int idx = blockIdx.x * 256 + threadIdx.x;   // NB*72 chunks total
  const int r = idx / 72, ch = idx - r * 72;        // 16B chunk in row
  const size_t o = (size_t)r * LDA + (size_t)ch * 16;
  union { u32x4 v4; unsigned char b[16]; } sv, vv;
  if (ch < 64) {                                    // state cols k<1024
    const float4* vp = (const float4*)(vdata + (size_t)r * 1024 + ch * 16);
    const bool u0 = rng_u01(USALT, (unsigned)r) < 0.5f;  // == EPI1 step-0
#pragma unroll
    for (int q = 0; q < 4; ++q) {
      const float4 f = vp[q];
      const float vs[4] = {f.x, f.y, f.z, f.w};
#pragma unroll
      for (int e = 0; e < 4; ++e) {
        const bool one = (vs[e] != 0.f);
        vv.b[q * 4 + e] = one ? BONE : (unsigned char)0;
        sv.b[q * 4 + e] = (u0 ? one : !one) ? BONE : (unsigned char)0;
      }
    }
    *(u32x4*)(V + o) = vv.v4;
    *(u32x4*)(S + o) = sv.v4;
  } else if (ch < 68) {                             // FiLM cols k 1024..1087
    const int j0 = (ch - 64) * 16;
#pragma unroll
    for (int e = 0; e < 16; ++e)
      sv.b[e] = qi8(X[(size_t)r * 64 + j0 + e], SXQ);
    *(u32x4*)(S + o) = sv.v4;
    *(u32x4*)(H + o) = sv.v4;
    *(u32x4*)(V + o) = sv.v4;
  } else {                                          // pad k 1088..1151 -> 0
    sv.v4 = (u32x4){0u, 0u, 0u, 0u};
    *(u32x4*)(S + o) = sv.v4;
    *(u32x4*)(H + o) = sv.v4;
    *(u32x4*)(V + o) = sv.v4;
  }
}

// per-row scalar finale: sb from rank-64 closed form, d1/d2 from bias-dots
__global__ __launch_bounds__(256) void k_final(
    const float* __restrict__ Xf, const float* __restrict__ aux,
    const float* __restrict__ pv0, const float* __restrict__ pv1, unsigned usalt,
    const float* __restrict__ spn_d, const float* __restrict__ spf_d,
    const float* __restrict__ spn_m, const float* __restrict__ spf_m,
    const float* __restrict__ vb_d, const float* __restrict__ vb_m,
    float* __restrict__ fdiff) {
  __shared__ float ax[65];
  int t = threadIdx.x;
  if (t < 65) ax[t] = aux[t];
  __syncthreads();
  int r = blockIdx.x * 256 + t;
  float sb = ax[64];
  const float* xr = Xf + (size_t)r * 64;
#pragma unroll
  for (int k = 0; k < 64; k++) sb += xr[k] * ax[k];
  const float dE = -pv0[r] + 2.f * pv1[r];
  const bool uu = rng_u01(usalt, (unsigned)r) < sigm(dE);
  const float d1 = vb_d[r], d2 = vb_m[r];
  float F_d = -lse2(d1 + spn_d[r], (sb - d1) + spf_d[r]);
  float vbn = uu ? d2 : (sb - d2);
  float F_m = -lse2(vbn + spn_m[r], (sb - vbn) + spf_m[r]);
  fdiff[r] = F_d - F_m;
}

__global__ __launch_bounds__(256) void k_reduce(const float* __restrict__ fdiff,
                                                float* __restrict__ out) {
  __shared__ float red[4];
  int t = threadIdx.x;
  float s = 0.f;
  for (int i = t; i < NB; i += 256) s += fdiff[i];
  for (int m = 32; m >= 1; m >>= 1) s += __shfl_xor(s, m, 64);
  if ((t & 63) == 0) red[t >> 6] = s;
  __syncthreads();
  if (t == 0) out[0] = (red[0] + red[1] + red[2] + red[3]) * (1.0f / (float)NB);
}

// ---------------------------------------------------------------------------
extern "C" void kernel_launch(void* const* d_in, const int* in_sizes, int n_in, void* d_out,
                              int out_size, void* d_ws, size_t ws_size, hipStream_t stream) {
  const float* vdata = (const float*)d_in[0];
  const float* cond = (const float*)d_in[1];
  const float* W = (const float*)d_in[2];
  const float* bb = (const float*)d_in[3];
  const float* cc = (const float*)d_in[4];
  const float* fc1w = (const float*)d_in[5];
  const float* fc1b = (const float*)d_in[6];
  const float* fc2w = (const float*)d_in[7];
  const float* fc2b = (const float*)d_in[8];
  float* out = (float*)d_out;

  char* wp = (char*)d_ws;
  auto alloc = [&](size_t bytes) {
    char* p = wp;
    wp += (bytes + 255) & ~(size_t)255;
    return p;
  };
  unsigned char* Wt = (unsigned char*)alloc((size_t)1152 * LDA);
  unsigned char* Wb = (unsigned char*)alloc((size_t)1152 * LDA);
  float* wcs = (float*)alloc(1024 * 4);
  float* X = (float*)alloc((size_t)NB * 64 * 4);
  float* Gb = (float*)alloc((size_t)1024 * 64 * 4);
  float* Gc = (float*)alloc((size_t)1024 * 64 * 4);
  float* cstb = (float*)alloc(1024 * 4);
  float* cstc = (float*)alloc(1024 * 4);
  float* aux = (float*)alloc(65 * 4);
  unsigned char* S = (unsigned char*)alloc((size_t)NB * LDA);
  unsigned char* H = (unsigned char*)alloc((size_t)NB * LDA);
  unsigned char* V = (unsigned char*)alloc((size_t)NB * LDA);
  // per-step dE accumulators: pair t at pall + (t+1)*2*NB, t=-1..9; then 6 arrays
  float* pall = (float*)alloc((size_t)(KSTEPS + 1 + 3) * 2 * NB * 4);
  float* spn_d = pall + (size_t)(KSTEPS + 1) * 2 * NB;
  float* spf_d = spn_d + NB;
  float* spn_m = spf_d + NB;
  float* spf_m = spn_m + NB;
  float* vb_d = spf_m + NB;
  float* vb_m = vb_d + NB;
  float* fdiff = (float*)alloc(NB * 4);
  auto P0 = [&](int t) { return pall + (size_t)(t + 1) * 2 * NB; };
  auto P1 = [&](int t) { return pall + (size_t)(t + 1) * 2 * NB + NB; };

  hipMemsetAsync(pall, 0, (size_t)(KSTEPS + 1 + 3) * 2 * NB * 4, stream);
  hipMemsetAsync(wcs, 0, 1024 * 4, stream);

  k_x<<<NB * 64 / 256, 256, 0, stream>>>(cond, fc1w, fc1b, X);
  k_g<<<1024 * 64 / 256, 256, 0, stream>>>(fc2w, fc2b, bb, cc, Gb, Gc, cstb, cstc);
  k_prepw<<<dim3(16, 16), 256, 0, stream>>>(W, Wt, Wb);
  k_prep<<<dim3(5, 1152), 256, 0, stream>>>(W, Gb, Gc, cstb, cstc, Wt, Wb);
  k_wcs<<<dim3(4, 16), 256, 0, stream>>>(W, wcs);
  k_aux<<<1, 128, 0, stream>>>(Gb, cstb, aux);
  k_sinit<<<NB * 72 / 256, 256, 0, stream>>>(vdata, X, S, H, V);

  for (int step = 0; step < KSTEPS; ++step) {
    // z1 = sW + c_mod (ext-K, +cstc epi); h ~ Bern(sigm(z1)) -> H
    gemm_bt<0><<<1024, 256, 0, stream>>>(S, Wt, H, cstc, nullptr, nullptr,
                                         nullptr, nullptr, 0u, nullptr, nullptr, nullptr,
                                         2000u + (unsigned)step);
    // z2 = hW^T + b_mod (ext-K, +cstb epi); u_t inline; dE partials; s_new -> S
    gemm_bt<1><<<1024, 256, 0, stream>>>(H, Wb, S, cstb, nullptr, nullptr,
                                         P0(step - 1), P1(step - 1), USALT + (unsigned)step,
                                         P0(step), P1(step), nullptr,
                                         3000u + (unsigned)step);
  }

  // Free-energy: softplus rows (n-tiles 0..7, split-acc; cm = accf*P+cstc) +
  // bias-dots (n-tile 8). i8 path (R21); cst in epilogue (R19).
  gemm_bt<2><<<2304, 256, 0, stream>>>(V, Wt, nullptr, cstc, wcs, X, nullptr, nullptr, 0u,
                                       spn_d, spf_d, vb_d, 0u);
  gemm_bt<2><<<2304, 256, 0, stream>>>(S, Wt, nullptr, cstc, wcs, X,
                                       P0(KSTEPS - 1), P1(KSTEPS - 1), USALT + KSTEPS,
                                       spn_m, spf_m, vb_m, 0u);
  k_final<<<NB / 256, 256, 0, stream>>>(X, aux, P0(KSTEPS - 1), P1(KSTEPS - 1), USALT + KSTEPS,
                                        spn_d, spf_d, spn_m, spf_m, vb_d, vb_m, fdiff);
  k_reduce<<<1, 256, 0, stream>>>(fdiff, out);
}

// Round 15
// 943.631 us; speedup vs baseline: 1.2941x; 1.2941x over previous
//
#include <hip/hip_runtime.h>
#include <hip/hip_bf16.h>
#include <stdint.h>

// SymmetricHyperRBM on MI355X. K=10 Gibbs chain + free-energy gap.
// R28 == R23 (best verified, 944.8us, absmax 0.0). Five structural
// alternatives measured and rejected: R18 counted-vmcnt two-barrier (null),
// R22 fragment-direct no-LDS (-20%: per-wave L1/L2 latency exposed),
// R24 1-wave private-LDS (occupancy 42->20%, -30%), R26 3-buffer 2-deep
// (occupancy 4->3 blk/CU, null-neg), R27 global-B fragments (FETCH +35%,
// scattered 16B reads thrash L2). The R23 shape — chain BM=128 4x(64x64),
// 2x12KB stage-ahead dbuf, ONE __syncthreads/iter, i8 mfma_i32_16x16x64 —
// is the empirical optimum; residual stall is the structural 2-phase
// overhead (m233) which every deeper pipeline traded away in occupancy.
// Carried: i8 states {0,7}, w=round(W*8192/7), x=round(X*128),
// g=round(G*64), p=2^-13, exact i32 accum (R21); NT=17 full unroll (R20);
// EPI1 old-S via LDS-staged swizzled tile (R20); KD=1088, cst in epilogue
// (R19); EPI2 split-acc, cmod/k_bmod eliminated (R16); vectorized k_sinit,
// parallel k_wcs (R23); fast softplus (R15); XCD swizzle; inline-u chain.

#define NB 16384
#define KSTEPS 10
#define LDA 1152           // bytes/row: 1024 state + 64 X + 1 const + 63 pad
#define KD 1088            // GEMM K-dim: 1024 state + 64 X (cst in epilogue)
#define NT 17              // KD/64 K-iterations (compile-time, fully unrolled)
#define SLS 136            // epilogue slab row stride in bytes (128 + 8 pad)
#define USALT 4000u
#define BONE ((unsigned char)7)     // binary-one storage value (i8)
#define PSC 0x1.0p-13f              // common int->value scale p
#define RWQ 1170.2857142857f        // 8192/7: W & cst quantizer
#define SGQ 64.0f                   // G quantizer
#define SXQ 128.0f                  // X quantizer

typedef __attribute__((ext_vector_type(4))) float f32x4;
typedef __attribute__((ext_vector_type(4))) int i32x4;
typedef __attribute__((ext_vector_type(4))) unsigned int u32x4;

__device__ __forceinline__ unsigned hash32(unsigned idx, unsigned salt) {
  unsigned x = idx + salt * 0x9E3779B9u;
  x = (x ^ (x >> 16)) * 0x7feb352du;
  x = (x ^ (x >> 15)) * 0x846ca68bu;
  return x ^ (x >> 16);
}
__device__ __forceinline__ float rng_u01(unsigned salt, unsigned idx) {
  return (float)(hash32(idx, salt) >> 8) * (1.0f / 16777216.0f);
}
__device__ __forceinline__ float sigm(float z) { return 1.0f / (1.0f + __expf(-z)); }
// fast softplus: max(z,0) + log(1+exp(-|z|)); v_exp/v_log based.
__device__ __forceinline__ float softplus_(float z) {
  return fmaxf(z, 0.f) + __logf(1.f + __expf(-fabsf(z)));
}
__device__ __forceinline__ float lse2(float a, float b) {
  float m = fmaxf(a, b);
  return m + log1pf(__expf(fminf(a, b) - m));
}
// saturating i8 quantizer (returns bit pattern)
__device__ __forceinline__ unsigned char qi8(float v, float s) {
  float x = rintf(v * s);
  x = fminf(fmaxf(x, -127.f), 127.f);
  return (unsigned char)(signed char)(int)x;
}
__device__ __forceinline__ void gl2lds16(const void* g, void* l) {
  __builtin_amdgcn_global_load_lds(
      (const __attribute__((address_space(1))) unsigned int*)g,
      (__attribute__((address_space(3))) unsigned int*)l, 16, 0, 0);
}

// ---------------------------------------------------------------------------
// C = A[16384 x KD] *i8* Bt[. x KD]^T (epilogue: z = acc*PSC + cst),
// mfma_i32_16x16x64_i8, BK=64 (ONE K-slice/iter), NT=17 fully unrolled,
// double-buffered LDS, ONE barrier/iter.
// Chain (EPI0/1): BM=128 tile, 4 waves x 64x64, grid 1024:
//   xcd=L&7, li=L>>3; m0 = xcd*2048 + (li&15)*128; n-tile = li>>4.
// EPI2: BM=64 tile, 4 waves x 32x64, grid 2304 (incl. bias n-tile 8):
//   m0 = xcd*2048 + (li&31)*64; n-tile = li>>5.
// EPI 0: h = bern(sigm(z1)) -> sh. EPI 1: u_t inline; p0+=sum z, p1+=sum v*z
// (v via LDS-staged old-S tile); s_new -> sh. EPI 2: split-acc (acc it<16 =
// vW; accf it==16 = X.Gc); n<8 softplus rows; n==8 bias-dots.
// ---------------------------------------------------------------------------
template <int EPI>
__global__ __launch_bounds__(256, 4) void gemm_bt(
    const unsigned char* __restrict__ A, const unsigned char* __restrict__ Bt,
    unsigned char* sh, const float* __restrict__ cst,
    const float* __restrict__ wcs, const float* __restrict__ Xf,
    const float* __restrict__ pv0, const float* __restrict__ pv1, unsigned usalt,
    float* __restrict__ p0, float* __restrict__ p1, float* __restrict__ p2,
    unsigned salt) {
  constexpr int MI = (EPI == 2 ? 2 : 4);   // 16-row tiles per wave (M dir)
  constexpr int BM = MI * 32;              // block rows: 64 (EPI2) / 128
  constexpr int ABYT = BM * 64;            // A-panel bytes/buffer: 4K / 8K
  constexpr int BUF = ABYT + 8192;         // buffer stride: 12K / 16K
  // epilogue slab BM x 136 B aliases the front after the loop (chain only);
  // EPI1 stages the old-S tile (BM x 128 B) into the buffer-1 region.
  __shared__ __align__(16) char smem[2 * BUF];
  unsigned char* newsl = (unsigned char*)smem;

  const int t = threadIdx.x;
  const int L = blockIdx.x;
  const int xcd = L & 7, li = L >> 3;
  constexpr int MMSK = (EPI == 2 ? 31 : 15);
  constexpr int NSH = (EPI == 2 ? 5 : 4);
  const int m0 = xcd * 2048 + (li & MMSK) * BM;
  const int n0 = (li >> NSH) * 128;
  const int lane = t & 63, wave = t >> 6;
  const int wm = (wave >> 1) * (MI * 16), wn = (wave & 1) * 64;
  const int lr = lane & 15, quad = lane >> 4;
  // staging: lane -> row = lane>>2, phys chunk lane&3; gathers LOGICAL chunk
  // q = (lane&3) ^ (row&3) ^ ((lane>>4)&3)   [double-XOR swizzle]
  const int row8 = lane >> 2;
  const int qch = (((lane & 3) ^ (row8 & 3) ^ ((lane >> 4) & 3)) << 4);
  // i8 K=64 fragment: lane holds k = quad*16..+16 -> logical chunk = quad;
  // phys chunk = quad ^ rx(row), one b128 read.
  const int rx = (lr & 3) ^ ((lr >> 2) & 3);
  const int kph = ((quad ^ rx) << 4);

  // staging base pointers; per-iter advance folds to immediates (unrolled)
  const unsigned char* gA0 = A + (size_t)(m0 + wave * (MI * 8) + row8) * LDA + qch;
  const unsigned char* gA1 = gA0 + (size_t)16 * LDA;  // chain only
  const unsigned char* gB0 = Bt + (size_t)(n0 + wave * 32 + row8) * LDA + qch;
  const unsigned char* gB1 = gB0 + (size_t)16 * LDA;

  auto stage = [&](int it, int bufb) {
    const int ko = it * 64;
    if constexpr (EPI == 2) {
      gl2lds16(gA0 + ko, smem + bufb + wave * 1024);
    } else {
      gl2lds16(gA0 + ko, smem + bufb + wave * 2048);
      gl2lds16(gA1 + ko, smem + bufb + wave * 2048 + 1024);
    }
    gl2lds16(gB0 + ko, smem + bufb + ABYT + wave * 2048);
    gl2lds16(gB1 + ko, smem + bufb + ABYT + wave * 2048 + 1024);
  };

  i32x4 acc[MI][4] = {};
  i32x4 accf[EPI == 2 ? MI : 1][4] = {};  // EPI2 only: FiLM iter = X.Gc

  // prologue: stage K-tile 0 into buffer 0
  stage(0, 0);
  __syncthreads();

#pragma unroll
  for (int it = 0; it < NT; ++it) {
    const int base = (it & 1) * BUF;          // compile-time per body
    if (it + 1 < NT) stage(it + 1, base ^ BUF);
    const char* sA = (const char*)smem + base;
    const char* sB = sA + ABYT;
    i32x4 af[MI], bfr[4];
#pragma unroll
    for (int i = 0; i < MI; i++)
      af[i] = *(const i32x4*)(sA + (wm + i * 16 + lr) * 64 + kph);
#pragma unroll
    for (int j = 0; j < 4; j++)
      bfr[j] = *(const i32x4*)(sB + (wn + j * 16 + lr) * 64 + kph);
    if (EPI == 2 && it >= 16) {  // FiLM iter (k 1024..1087) -> accf
#pragma unroll
      for (int i = 0; i < MI; i++)
#pragma unroll
        for (int j = 0; j < 4; j++)
          accf[i][j] = __builtin_amdgcn_mfma_i32_16x16x64_i8(af[i], bfr[j], accf[i][j], 0, 0, 0);
    } else {
#pragma unroll
      for (int i = 0; i < MI; i++)
#pragma unroll
        for (int j = 0; j < 4; j++)
          acc[i][j] = __builtin_amdgcn_mfma_i32_16x16x64_i8(af[i], bfr[j], acc[i][j], 0, 0, 0);
    }
    // ONE barrier per iter: its vmcnt(0) drain covers the prefetch (in
    // flight across the whole compute phase) and orders reads-of-base
    // before the next overwrite.
    __syncthreads();
  }

  // per-thread cst values for this thread's 4 column slots (L1-resident)
  float cst_j[4];
  if constexpr (EPI != 2) {
#pragma unroll
    for (int j = 0; j < 4; j++) cst_j[j] = cst[n0 + wn + j * 16 + lr];
  }

  // C/D layout (m89, dtype-independent): col = lane&15, row = quad*4 + reg
  if constexpr (EPI == 2) {
    if (n0 >= 1024) {  // bias-dot tile: cols 1024..1088 = [Gb-dots | cstb]
#pragma unroll
      for (int i = 0; i < MI; i++)
#pragma unroll
        for (int rg = 0; rg < 4; rg++) {
          const int r = m0 + wm + i * 16 + quad * 4 + rg;
          float pb = 0.f;
          if (wn == 0) {  // cg = j*16+lr in 0..63: G-dots with X[r]
#pragma unroll
            for (int j = 0; j < 4; j++)
              pb += (float)acc[i][j][rg] * Xf[(size_t)r * 64 + j * 16 + lr];
            pb *= (1.f / 448.f);            // /(7 * SGQ)
          } else {        // col 1088 (j==0,lr==0): cst-dot
            if (lr == 0) pb = (float)acc[i][0][rg] * PSC;
          }
#pragma unroll
          for (int msk = 1; msk < 16; msk <<= 1) pb += __shfl_xor(pb, msk, 64);
          if (lr == 0) atomicAdd(&p2[r], pb);
        }
      return;
    }
    float cstc_j[4];
#pragma unroll
    for (int j = 0; j < 4; j++) cstc_j[j] = cst[n0 + wn + j * 16 + lr];
#pragma unroll
    for (int i = 0; i < MI; i++)
#pragma unroll
      for (int rg = 0; rg < 4; rg++) {
        const int r = m0 + wm + i * 16 + quad * 4 + rg;
        bool uu = true;
        if (pv0 != nullptr) {
          const float dE = -pv0[r] + 2.f * pv1[r];
          uu = rng_u01(usalt, (unsigned)r) < sigm(dE);
        }
        float sn = 0.f, sf = 0.f;
#pragma unroll
        for (int j = 0; j < 4; j++) {
          const int n = n0 + wn + j * 16 + lr;
          const float vw = (float)acc[i][j][rg] * PSC;
          const float cm = (float)accf[i][j][rg] * PSC + cstc_j[j];
          const float s1 = softplus_(vw + cm);
          const float s2 = softplus_(wcs[n] - vw + cm);
          sn += uu ? s1 : s2;
          sf += uu ? s2 : s1;
        }
#pragma unroll
        for (int msk = 1; msk < 16; msk <<= 1) {
          sn += __shfl_xor(sn, msk, 64);
          sf += __shfl_xor(sf, msk, 64);
        }
        if (lr == 0) { atomicAdd(&p0[r], sn); atomicAdd(&p1[r], sf); }
      }
    return;
  }

  if constexpr (EPI == 1) {  // z-sums with v from OLD s; u_t inline
    // Stage this block's OLD-S tile (BM x 128 B) into the buffer-1 region
    // (dead after the loop: last tile computed in buffer 0 since NT odd).
    // m173: linear LDS dest + PRE-SWIZZLED global source, so lds chunk c of
    // row r holds global chunk c ^ ((r>>2)&3).
    {
      const int rb = wave * (MI * 8);            // 32 rows per wave (BM=128)
#pragma unroll
      for (int q = 0; q < 4; ++q) {
        const int row = rb + q * 8 + (lane >> 3);
        const int sc = (lane & 7) ^ ((row >> 2) & 3);
        gl2lds16(sh + (size_t)(m0 + row) * LDA + n0 + sc * 16,
                 (unsigned char*)smem + BUF + (rb + q * 8) * 128);
      }
    }
    __syncthreads();  // drains vmcnt -> old-S tile published in LDS
    const unsigned char* osl = (const unsigned char*)smem + BUF;
#pragma unroll
    for (int i = 0; i < MI; i++)
#pragma unroll
      for (int rg = 0; rg < 4; rg++) {
        const int r = m0 + wm + i * 16 + quad * 4 + rg;
        const int rowl = wm + i * 16 + quad * 4 + rg;
        const float dE = -pv0[r] + 2.f * pv1[r];
        const bool uu = rng_u01(usalt, (unsigned)r) < sigm(dE);
        float q0 = 0.f, q1 = 0.f;
#pragma unroll
        for (int j = 0; j < 4; ++j) {
          const float z = (float)acc[i][j][rg] * PSC + cst_j[j];
          // read-side swizzle: (rowl>>2)&3 == quad for our row decomposition
          const int pc = ((wn >> 4) + j) ^ quad;
          const float so = (osl[rowl * 128 + pc * 16 + lr] != 0) ? 1.f : 0.f;
          const float v = uu ? so : 1.f - so;
          q0 += z; q1 += v * z;
        }
#pragma unroll
        for (int msk = 1; msk < 16; msk <<= 1) {
          q0 += __shfl_xor(q0, msk, 64);
          q1 += __shfl_xor(q1, msk, 64);
        }
        if (lr == 0) { atomicAdd(&p0[r], q0); atomicAdd(&p1[r], q1); }
      }
    __syncthreads();  // all old-S reads done before slab overwrites [BUF,..)
  }

  // EPI 0/1: sample into BM-row slab, 1 barrier, coalesced store
#pragma unroll
  for (int i = 0; i < MI; ++i)
#pragma unroll
    for (int rg = 0; rg < 4; ++rg) {
      const int rowl = wm + i * 16 + quad * 4 + rg;  // 0..BM-1 in tile
      const int r = m0 + rowl;
#pragma unroll
      for (int jp = 0; jp < 2; ++jp) {
        const unsigned x = hash32((unsigned)(r << 10) + (unsigned)(n0 + wn + jp * 16 + lr), salt);
        const float f0 = (float)(x & 0xFFFFu), f1 = (float)(x >> 16);
        const float z0 = (float)acc[i][jp][rg] * PSC + cst_j[jp];
        const float z1v = (float)acc[i][jp + 2][rg] * PSC + cst_j[jp + 2];
        newsl[rowl * SLS + wn + jp * 16 + lr] =
            (f0 * __expf(-z0) < 65536.f - f0) ? BONE : (unsigned char)0;
        newsl[rowl * SLS + wn + (jp + 2) * 16 + lr] =
            (f1 * __expf(-z1v) < 65536.f - f1) ? BONE : (unsigned char)0;
      }
    }
  __syncthreads();
#pragma unroll
  for (int p = 0; p < BM / 32; ++p) {  // BM rows x 128 B, fully coalesced
    const int c = p * 256 + t, rowl = c >> 3, chk = c & 7;
    const u32x4 vv = *(const u32x4*)(newsl + rowl * SLS + chk * 16);
    *(u32x4*)(sh + (size_t)(m0 + rowl) * LDA + n0 + chk * 16) = vv;
  }
}

// ------------------------- setup / small kernels ---------------------------
__global__ __launch_bounds__(256) void k_x(const float* __restrict__ cond,
                                           const float* __restrict__ fc1w,
                                           const float* __restrict__ fc1b, float* __restrict__ X) {
  int idx = blockIdx.x * 256 + threadIdx.x;
  int r = idx >> 6, k = idx & 63;
  X[idx] = tanhf(cond[r] * fc1w[k] + fc1b[k]);
}

__global__ __launch_bounds__(256) void k_g(const float* __restrict__ fc2w,
                                           const float* __restrict__ fc2b,
                                           const float* __restrict__ b, const float* __restrict__ c,
                                           float* __restrict__ Gb, float* __restrict__ Gc,
                                           float* __restrict__ cstb, float* __restrict__ cstc) {
  int idx = blockIdx.x * 256 + threadIdx.x;
  int j = idx >> 6, k = idx & 63;
  Gb[idx] = fc2w[(size_t)j * 64 + k] * b[j] + fc2w[(size_t)(1024 + j) * 64 + k];
  Gc[idx] = fc2w[(size_t)(2048 + j) * 64 + k] * c[j] + fc2w[(size_t)(3072 + j) * 64 + k];
  if (k == 0) {
    cstb[j] = b[j] + fc2b[j] * b[j] + fc2b[1024 + j];
    cstc[j] = c[j] + fc2b[2048 + j] * c[j] + fc2b[3072 + j];
  }
}

// i8 pack. Wt rows n<1024: [W^T(RWQ)|Gc(SGQ)|cst|pad]; rows 1024..1087:
// Gb-col profiles (SGQ); row 1088: cstb (RWQ). Wb mirror with W/Gb/cstb.
// Rows >=1024 are zero at k>=1024 -> EPI2 bias-tile accf==0.
__global__ __launch_bounds__(256) void k_prep(const float* __restrict__ W,
                                              const float* __restrict__ Gb,
                                              const float* __restrict__ Gc,
                                              const float* __restrict__ cstb,
                                              const float* __restrict__ cstc,
                                              unsigned char* __restrict__ Wt,
                                              unsigned char* __restrict__ Wb) {
  int k = blockIdx.x * 256 + threadIdx.x;
  int n = blockIdx.y;
  if (k >= LDA) return;
  unsigned char wt = 0, wb = 0;
  if (n < 1024) {
    if (k < 1024) {
      wt = qi8(W[(size_t)k * 1024 + n], RWQ);
      wb = qi8(W[(size_t)n * 1024 + k], RWQ);
    } else if (k < 1088) {
      int j = k - 1024;
      wt = qi8(Gc[(size_t)n * 64 + j], SGQ);
      wb = qi8(Gb[(size_t)n * 64 + j], SGQ);
    } else if (k == 1088) {  // unused at KD=1088
      wt = qi8(cstc[n], RWQ);
      wb = qi8(cstb[n], RWQ);
    }
  } else if (k < 1024) {
    if (n < 1088) wt = qi8(Gb[(size_t)k * 64 + (n - 1024)], SGQ);
    else if (n == 1088) wt = qi8(cstb[k], RWQ);
  }
  Wt[(size_t)n * LDA + k] = wt;
  Wb[(size_t)n * LDA + k] = wb;
}

// 64 blocks x (256 n, 64 i) partials + atomicAdd (wcs pre-zeroed)
__global__ __launch_bounds__(256) void k_wcs(const float* __restrict__ W, float* __restrict__ wcs) {
  int n = blockIdx.x * 256 + threadIdx.x;
  int i0 = blockIdx.y * 64;
  float s = 0.f;
  for (int i = i0; i < i0 + 64; i++) s += W[(size_t)i * 1024 + n];
  atomicAdd(&wcs[n], s);
}

// aux[k<64] = sum_j Gb[j][k]; aux[64] = sum_j cstb[j]
__global__ __launch_bounds__(128) void k_aux(const float* __restrict__ Gb,
                                             const float* __restrict__ cstb,
                                             float* __restrict__ aux) {
  int t = threadIdx.x;
  if (t < 64) {
    float s = 0.f;
    for (int j = 0; j < 1024; j++) s += Gb[(size_t)j * 64 + t];
    aux[t] = s;
  } else if (t == 64) {
    float s = 0.f;
    for (int j = 0; j < 1024; j++) s += cstb[j];
    aux[64] = s;
  }
}

// vectorized init: one 16-B chunk per thread (was 1 byte/lane stores).
// Values bit-identical to the scalar version (same u0 formula/quantizers).
__global__ __launch_bounds__(256) void k_sinit(const float* __restrict__ vdata,
                                               const float* __restrict__ X,
                                               unsigned char* __restrict__ S,
                                               unsigned char* __restrict__ H,
                                               unsigned char* __restrict__ V) {
  const int idx = blockIdx.x * 256 + threadIdx.x;   // NB*72 chunks total
  const int r = idx / 72, ch = idx - r * 72;        // 16B chunk in row
  const size_t o = (size_t)r * LDA + (size_t)ch * 16;
  union { u32x4 v4; unsigned char b[16]; } sv, vv;
  if (ch < 64) {                                    // state cols k<1024
    const float4* vp = (const float4*)(vdata + (size_t)r * 1024 + ch * 16);
    const bool u0 = rng_u01(USALT, (unsigned)r) < 0.5f;  // == EPI1 step-0
#pragma unroll
    for (int q = 0; q < 4; ++q) {
      const float4 f = vp[q];
      const float vs[4] = {f.x, f.y, f.z, f.w};
#pragma unroll
      for (int e = 0; e < 4; ++e) {
        const bool one = (vs[e] != 0.f);
        vv.b[q * 4 + e] = one ? BONE : (unsigned char)0;
        sv.b[q * 4 + e] = (u0 ? one : !one) ? BONE : (unsigned char)0;
      }
    }
    *(u32x4*)(V + o) = vv.v4;
    *(u32x4*)(S + o) = sv.v4;
  } else if (ch < 68) {                             // FiLM cols k 1024..1087
    const int j0 = (ch - 64) * 16;
#pragma unroll
    for (int e = 0; e < 16; ++e)
      sv.b[e] = qi8(X[(size_t)r * 64 + j0 + e], SXQ);
    *(u32x4*)(S + o) = sv.v4;
    *(u32x4*)(H + o) = sv.v4;
    *(u32x4*)(V + o) = sv.v4;
  } else {                                          // pad k 1088..1151 -> 0
    sv.v4 = (u32x4){0u, 0u, 0u, 0u};
    *(u32x4*)(S + o) = sv.v4;
    *(u32x4*)(H + o) = sv.v4;
    *(u32x4*)(V + o) = sv.v4;
  }
}

// per-row scalar finale: sb from rank-64 closed form, d1/d2 from bias-dots
__global__ __launch_bounds__(256) void k_final(
    const float* __restrict__ Xf, const float* __restrict__ aux,
    const float* __restrict__ pv0, const float* __restrict__ pv1, unsigned usalt,
    const float* __restrict__ spn_d, const float* __restrict__ spf_d,
    const float* __restrict__ spn_m, const float* __restrict__ spf_m,
    const float* __restrict__ vb_d, const float* __restrict__ vb_m,
    float* __restrict__ fdiff) {
  __shared__ float ax[65];
  int t = threadIdx.x;
  if (t < 65) ax[t] = aux[t];
  __syncthreads();
  int r = blockIdx.x * 256 + t;
  float sb = ax[64];
  const float* xr = Xf + (size_t)r * 64;
#pragma unroll
  for (int k = 0; k < 64; k++) sb += xr[k] * ax[k];
  const float dE = -pv0[r] + 2.f * pv1[r];
  const bool uu = rng_u01(usalt, (unsigned)r) < sigm(dE);
  const float d1 = vb_d[r], d2 = vb_m[r];
  float F_d = -lse2(d1 + spn_d[r], (sb - d1) + spf_d[r]);
  float vbn = uu ? d2 : (sb - d2);
  float F_m = -lse2(vbn + spn_m[r], (sb - vbn) + spf_m[r]);
  fdiff[r] = F_d - F_m;
}

__global__ __launch_bounds__(256) void k_reduce(const float* __restrict__ fdiff,
                                                float* __restrict__ out) {
  __shared__ float red[4];
  int t = threadIdx.x;
  float s = 0.f;
  for (int i = t; i < NB; i += 256) s += fdiff[i];
  for (int m = 32; m >= 1; m >>= 1) s += __shfl_xor(s, m, 64);
  if ((t & 63) == 0) red[t >> 6] = s;
  __syncthreads();
  if (t == 0) out[0] = (red[0] + red[1] + red[2] + red[3]) * (1.0f / (float)NB);
}

// ---------------------------------------------------------------------------
extern "C" void kernel_launch(void* const* d_in, const int* in_sizes, int n_in, void* d_out,
                              int out_size, void* d_ws, size_t ws_size, hipStream_t stream) {
  const float* vdata = (const float*)d_in[0];
  const float* cond = (const float*)d_in[1];
  const float* W = (const float*)d_in[2];
  const float* bb = (const float*)d_in[3];
  const float* cc = (const float*)d_in[4];
  const float* fc1w = (const float*)d_in[5];
  const float* fc1b = (const float*)d_in[6];
  const float* fc2w = (const float*)d_in[7];
  const float* fc2b = (const float*)d_in[8];
  float* out = (float*)d_out;

  char* wp = (char*)d_ws;
  auto alloc = [&](size_t bytes) {
    char* p = wp;
    wp += (bytes + 255) & ~(size_t)255;
    return p;
  };
  unsigned char* Wt = (unsigned char*)alloc((size_t)1152 * LDA);
  unsigned char* Wb = (unsigned char*)alloc((size_t)1152 * LDA);
  float* wcs = (float*)alloc(1024 * 4);
  float* X = (float*)alloc((size_t)NB * 64 * 4);
  float* Gb = (float*)alloc((size_t)1024 * 64 * 4);
  float* Gc = (float*)alloc((size_t)1024 * 64 * 4);
  float* cstb = (float*)alloc(1024 * 4);
  float* cstc = (float*)alloc(1024 * 4);
  float* aux = (float*)alloc(65 * 4);
  unsigned char* S = (unsigned char*)alloc((size_t)NB * LDA);
  unsigned char* H = (unsigned char*)alloc((size_t)NB * LDA);
  unsigned char* V = (unsigned char*)alloc((size_t)NB * LDA);
  // per-step dE accumulators: pair t at pall + (t+1)*2*NB, t=-1..9; then 6 arrays
  float* pall = (float*)alloc((size_t)(KSTEPS + 1 + 3) * 2 * NB * 4);
  float* spn_d = pall + (size_t)(KSTEPS + 1) * 2 * NB;
  float* spf_d = spn_d + NB;
  float* spn_m = spf_d + NB;
  float* spf_m = spn_m + NB;
  float* vb_d = spf_m + NB;
  float* vb_m = vb_d + NB;
  float* fdiff = (float*)alloc(NB * 4);
  auto P0 = [&](int t) { return pall + (size_t)(t + 1) * 2 * NB; };
  auto P1 = [&](int t) { return pall + (size_t)(t + 1) * 2 * NB + NB; };

  hipMemsetAsync(pall, 0, (size_t)(KSTEPS + 1 + 3) * 2 * NB * 4, stream);
  hipMemsetAsync(wcs, 0, 1024 * 4, stream);

  k_x<<<NB * 64 / 256, 256, 0, stream>>>(cond, fc1w, fc1b, X);
  k_g<<<1024 * 64 / 256, 256, 0, stream>>>(fc2w, fc2b, bb, cc, Gb, Gc, cstb, cstc);
  k_prep<<<dim3(5, 1152), 256, 0, stream>>>(W, Gb, Gc, cstb, cstc, Wt, Wb);
  k_wcs<<<dim3(4, 16), 256, 0, stream>>>(W, wcs);
  k_aux<<<1, 128, 0, stream>>>(Gb, cstb, aux);
  k_sinit<<<NB * 72 / 256, 256, 0, stream>>>(vdata, X, S, H, V);

  for (int step = 0; step < KSTEPS; ++step) {
    // z1 = sW + c_mod (ext-K, +cstc epi); h ~ Bern(sigm(z1)) -> H
    gemm_bt<0><<<1024, 256, 0, stream>>>(S, Wt, H, cstc, nullptr, nullptr,
                                         nullptr, nullptr, 0u, nullptr, nullptr, nullptr,
                                         2000u + (unsigned)step);
    // z2 = hW^T + b_mod (ext-K, +cstb epi); u_t inline; dE partials; s_new -> S
    gemm_bt<1><<<1024, 256, 0, stream>>>(H, Wb, S, cstb, nullptr, nullptr,
                                         P0(step - 1), P1(step - 1), USALT + (unsigned)step,
                                         P0(step), P1(step), nullptr,
                                         3000u + (unsigned)step);
  }

  // Free-energy: softplus rows (n-tiles 0..7, split-acc; cm = accf*P+cstc) +
  // bias-dots (n-tile 8). i8 path (R21); cst in epilogue (R19).
  gemm_bt<2><<<2304, 256, 0, stream>>>(V, Wt, nullptr, cstc, wcs, X, nullptr, nullptr, 0u,
                                       spn_d, spf_d, vb_d, 0u);
  gemm_bt<2><<<2304, 256, 0, stream>>>(S, Wt, nullptr, cstc, wcs, X,
                                       P0(KSTEPS - 1), P1(KSTEPS - 1), USALT + KSTEPS,
                                       spn_m, spf_m, vb_m, 0u);
  k_final<<<NB / 256, 256, 0, stream>>>(X, aux, P0(KSTEPS - 1), P1(KSTEPS - 1), USALT + KSTEPS,
                                        spn_d, spf_d, spn_m, spf_m, vb_d, vb_m, fdiff);
  k_reduce<<<1, 256, 0, stream>>>(fdiff, out);
}